// Round 3
// baseline (11664.566 us; speedup 1.0000x reference)
//
#include <hip/hip_runtime.h>

#define S_TOT 3872
#define C_DIM 1536
#define NHEAD 12
#define DHEAD 128
#define HALF  64
#define TT 8
#define HH 22
#define WW 22

typedef __bf16 bf16x8 __attribute__((ext_vector_type(8)));
typedef float  f32x4  __attribute__((ext_vector_type(4)));
typedef unsigned short u16x8 __attribute__((ext_vector_type(8)));

__device__ __forceinline__ float bf2f(unsigned short u) {
    unsigned int v = ((unsigned int)u) << 16;
    float f;
    __builtin_memcpy(&f, &v, 4);
    return f;
}
__device__ __forceinline__ float f_lo(unsigned int w) {
    unsigned int v = w << 16;
    float f; __builtin_memcpy(&f, &v, 4); return f;
}
__device__ __forceinline__ float f_hi(unsigned int w) {
    unsigned int v = w & 0xffff0000u;
    float f; __builtin_memcpy(&f, &v, 4); return f;
}
__device__ __forceinline__ unsigned short f2bf(float f) {
    unsigned int u;
    __builtin_memcpy(&u, &f, 4);
    unsigned int lsb = (u >> 16) & 1u;
    u += 0x7fffu + lsb;
    return (unsigned short)(u >> 16);
}
// dtype-agnostic external load: flag!=0 -> buffer is f32, else bf16
__device__ __forceinline__ float ldin(const void* p, size_t i, int isf32) {
    if (isf32) return ((const float*)p)[i];
    return bf2f(((const unsigned short*)p)[i]);
}

// ---------------- dtype detector: 1 block, writes flag ----------------
// bf16 N(0,1) data: exponent field in [112,143] for ~100% of elements.
// f32 data read as u16: low halves have ~uniform exponent field (~12.5% hit).
__global__ void detect(const unsigned short* __restrict__ x, int* __restrict__ flag) {
    __shared__ int cnt;
    if (threadIdx.x == 0) cnt = 0;
    __syncthreads();
    int c = 0;
    for (int i = 0; i < 8; ++i) {
        unsigned short u = x[threadIdx.x * 8 + i];
        int e = (u >> 7) & 0xFF;
        if (e >= 112 && e <= 143) c++;
    }
    atomicAdd(&cnt, c);
    __syncthreads();
    if (threadIdx.x == 0) *flag = (cnt >= 1900) ? 0 : 1;   // 1 => f32 inputs
}

// ---------------- LayerNorm stats: per column s over C ----------------
__global__ __launch_bounds__(256) void ln_stats(const void* __restrict__ x,
                                                const int* __restrict__ flag,
                                                float* __restrict__ meanb,
                                                float* __restrict__ rstdb) {
    int isf32 = *flag;
    int s = blockIdx.x * 256 + threadIdx.x;
    if (s >= S_TOT) return;
    float sum = 0.f, sumsq = 0.f;
    for (int c = 0; c < C_DIM; ++c) {
        float v = ldin(x, (size_t)c * S_TOT + s, isf32);
        sum += v; sumsq += v * v;
    }
    float m = sum * (1.0f / C_DIM);
    float var = sumsq * (1.0f / C_DIM) - m * m;
    meanb[s] = m;
    rstdb[s] = rsqrtf(var + 1e-6f);
}

// ------------- Normalize + transpose (C,S) -> (S,C) bf16 --------------
__global__ __launch_bounds__(256) void ln_norm_t(const void* __restrict__ x,
                                                 const int* __restrict__ flag,
                                                 const float* __restrict__ meanb,
                                                 const float* __restrict__ rstdb,
                                                 unsigned short* __restrict__ xn) {
    int isf32 = *flag;
    __shared__ float tile[32][33];   // [c_local][s_local]
    int s0 = blockIdx.x * 32, c0 = blockIdx.y * 32;
    int tx = threadIdx.x, ty = threadIdx.y;   // (32,8)
    for (int r = 0; r < 4; ++r) {
        int cl = ty + 8 * r;
        tile[cl][tx] = ldin(x, (size_t)(c0 + cl) * S_TOT + (s0 + tx), isf32);
    }
    __syncthreads();
    for (int r = 0; r < 4; ++r) {
        int sl = ty + 8 * r;
        int s = s0 + sl, c = c0 + tx;
        xn[(size_t)s * C_DIM + c] = f2bf((tile[tx][sl] - meanb[s]) * rstdb[s]);
    }
}

// --------------- MFMA GEMM: D(MxN) = A(MxK) * W(NxK)^T + bias, bf16 out
// A is always internal bf16; W/bias are external (dual-dtype).
#define BM 64
#define BN 64
#define BK 32
#define LDA_P 40   // padded LDS stride (elements)

__global__ __launch_bounds__(256) void gemm_bias(const unsigned short* __restrict__ A,
                                                 const void* __restrict__ Bw,
                                                 const void* __restrict__ bias,
                                                 const int* __restrict__ flag,
                                                 unsigned short* __restrict__ D) {
    int isf32 = *flag;
    __shared__ __align__(16) unsigned short As[BM * LDA_P];
    __shared__ __align__(16) unsigned short Bs[BN * LDA_P];
    int m0 = blockIdx.x * BM;
    int n0 = blockIdx.y * BN;
    int tid = threadIdx.x;
    int wave = tid >> 6, lane = tid & 63;
    int srow = tid >> 2;            // 0..63
    int scol = (tid & 3) * 8;       // 0,8,16,24

    f32x4 acc0 = {0.f,0.f,0.f,0.f};
    f32x4 acc1 = {0.f,0.f,0.f,0.f};
    f32x4 acc2 = {0.f,0.f,0.f,0.f};
    f32x4 acc3 = {0.f,0.f,0.f,0.f};

    int ga = m0 + srow; if (ga >= S_TOT) ga = S_TOT - 1;
    int gb = n0 + srow;
    int ar = 16 * wave + (lane & 15);
    int koff = (lane >> 4) * 8;

    for (int k0 = 0; k0 < C_DIM; k0 += BK) {
        u16x8 av = *(const u16x8*)(A + (size_t)ga * C_DIM + k0 + scol);
        u16x8 bv;
        if (isf32) {
            const float* bp = (const float*)Bw + (size_t)gb * C_DIM + k0 + scol;
            float4 f0 = *(const float4*)(bp);
            float4 f1 = *(const float4*)(bp + 4);
            bv[0] = f2bf(f0.x); bv[1] = f2bf(f0.y); bv[2] = f2bf(f0.z); bv[3] = f2bf(f0.w);
            bv[4] = f2bf(f1.x); bv[5] = f2bf(f1.y); bv[6] = f2bf(f1.z); bv[7] = f2bf(f1.w);
        } else {
            bv = *(const u16x8*)((const unsigned short*)Bw + (size_t)gb * C_DIM + k0 + scol);
        }
        *(u16x8*)(&As[srow * LDA_P + scol]) = av;
        *(u16x8*)(&Bs[srow * LDA_P + scol]) = bv;
        __syncthreads();
        bf16x8 afrag = *(const bf16x8*)(&As[ar * LDA_P + koff]);
        bf16x8 b0 = *(const bf16x8*)(&Bs[( 0 + (lane & 15)) * LDA_P + koff]);
        bf16x8 b1 = *(const bf16x8*)(&Bs[(16 + (lane & 15)) * LDA_P + koff]);
        bf16x8 b2 = *(const bf16x8*)(&Bs[(32 + (lane & 15)) * LDA_P + koff]);
        bf16x8 b3 = *(const bf16x8*)(&Bs[(48 + (lane & 15)) * LDA_P + koff]);
        acc0 = __builtin_amdgcn_mfma_f32_16x16x32_bf16(afrag, b0, acc0, 0, 0, 0);
        acc1 = __builtin_amdgcn_mfma_f32_16x16x32_bf16(afrag, b1, acc1, 0, 0, 0);
        acc2 = __builtin_amdgcn_mfma_f32_16x16x32_bf16(afrag, b2, acc2, 0, 0, 0);
        acc3 = __builtin_amdgcn_mfma_f32_16x16x32_bf16(afrag, b3, acc3, 0, 0, 0);
        __syncthreads();
    }

    int row_base = m0 + 16 * wave + ((lane >> 4) * 4);
    int col = lane & 15;
    f32x4 accs[4] = {acc0, acc1, acc2, acc3};
    for (int nt = 0; nt < 4; ++nt) {
        int gn = n0 + 16 * nt + col;
        float bvf = ldin(bias, gn, isf32);
        for (int r = 0; r < 4; ++r) {
            int gm = row_base + r;
            if (gm < S_TOT) D[(size_t)gm * C_DIM + gn] = f2bf(accs[nt][r] + bvf);
        }
    }
}

// ---------- RMSNorm (full C) + RoPE, IN-PLACE on bf16 (S,C) -----------
// cos/sin computed inline (f32; error ~2e-6 << bf16 rounding 4e-3).
__global__ __launch_bounds__(256) void rms_rope(unsigned short* __restrict__ buf,
                                                const void* __restrict__ g,
                                                const int* __restrict__ flag) {
    int isf32 = *flag;
    int s = blockIdx.x;
    unsigned short* row = buf + (size_t)s * C_DIM;
    int tid = threadIdx.x;
    float ss = 0.f;
    for (int i = 0; i < 6; ++i) {
        float v = bf2f(row[tid + 256 * i]);
        ss += v * v;
    }
    for (int off = 32; off; off >>= 1) ss += __shfl_down(ss, off, 64);
    __shared__ float wsum[4];
    __shared__ float scale_sh;
    if ((tid & 63) == 0) wsum[tid >> 6] = ss;
    __syncthreads();
    if (tid == 0) {
        float tot = wsum[0] + wsum[1] + wsum[2] + wsum[3];
        scale_sh = rsqrtf(tot * (1.0f / C_DIM) + 1e-6f);
    }
    __syncthreads();
    float scale = scale_sh;

    int t  = s / (HH * WW);
    int rm = s % (HH * WW);
    int hh = rm / WW, ww = rm % WW;

    float e[3][2];
    int cols[3];
    for (int i = 0; i < 3; ++i) {
        int p = tid + 256 * i;        // pair index 0..767
        int j = p & 63;
        int col0 = (p >> 6) * DHEAD + 2 * j;
        cols[i] = col0;
        float e0 = bf2f(row[col0])     * scale * ldin(g, col0, isf32);
        float e1 = bf2f(row[col0 + 1]) * scale * ldin(g, col0 + 1, isf32);
        float pos, fr;
        if (j < 22)       { pos = (float)t;  fr = (float)j        * (1.0f / 22.0f); }
        else if (j < 43)  { pos = (float)hh; fr = (float)(j - 22) * (1.0f / 21.0f); }
        else              { pos = (float)ww; fr = (float)(j - 43) * (1.0f / 21.0f); }
        float ang = pos * expf(fr * -9.210340371976184f);   // *10000^-fr
        float c = cosf(ang), sn = sinf(ang);
        e[i][0] = e0 * c - e1 * sn;
        e[i][1] = e0 * sn + e1 * c;
    }
    for (int i = 0; i < 3; ++i) {
        row[cols[i]]     = f2bf(e[i][0]);
        row[cols[i] + 1] = f2bf(e[i][1]);
    }
}

// ------------------- Attention: one block per (h, q) ------------------
__global__ __launch_bounds__(256) void attn(const unsigned short* __restrict__ q,
                                            const unsigned short* __restrict__ k,
                                            const unsigned short* __restrict__ v,
                                            unsigned short* __restrict__ o) {
    int h  = blockIdx.x / S_TOT;
    int qi = blockIdx.x % S_TOT;
    __shared__ float qs[DHEAD];
    __shared__ float logits[S_TOT];
    __shared__ float red[4];
    __shared__ float part[4][DHEAD];
    int tid = threadIdx.x;
    const float scale = 0.08838834764831845f;  // 1/sqrt(128)

    if (tid < DHEAD) qs[tid] = bf2f(q[(size_t)qi * C_DIM + h * DHEAD + tid]) * scale;
    __syncthreads();

    // phase 1: logits
    float lmax = -1e30f;
    for (int j = tid; j < S_TOT; j += 256) {
        const unsigned short* kr = k + (size_t)j * C_DIM + h * DHEAD;
        float dot = 0.f;
        #pragma unroll
        for (int i = 0; i < DHEAD; i += 8) {
            uint4 pk = *(const uint4*)(kr + i);
            dot += qs[i + 0] * f_lo(pk.x) + qs[i + 1] * f_hi(pk.x);
            dot += qs[i + 2] * f_lo(pk.y) + qs[i + 3] * f_hi(pk.y);
            dot += qs[i + 4] * f_lo(pk.z) + qs[i + 5] * f_hi(pk.z);
            dot += qs[i + 6] * f_lo(pk.w) + qs[i + 7] * f_hi(pk.w);
        }
        logits[j] = dot;
        lmax = fmaxf(lmax, dot);
    }
    for (int off = 32; off; off >>= 1) lmax = fmaxf(lmax, __shfl_down(lmax, off, 64));
    if ((tid & 63) == 0) red[tid >> 6] = lmax;
    __syncthreads();
    float m = fmaxf(fmaxf(red[0], red[1]), fmaxf(red[2], red[3]));

    // phase 2: exp + sum
    float lsum = 0.f;
    for (int j = tid; j < S_TOT; j += 256) {
        float e = __expf(logits[j] - m);
        logits[j] = e;
        lsum += e;
    }
    for (int off = 32; off; off >>= 1) lsum += __shfl_down(lsum, off, 64);
    __syncthreads();                  // everyone done reading red (max)
    if ((tid & 63) == 0) red[tid >> 6] = lsum;
    __syncthreads();
    float inv = 1.0f / (red[0] + red[1] + red[2] + red[3]);

    // phase 3: o = P * V  (thread: 2 dims, 1 of 4 j-groups)
    int ig = (tid & 63) * 2;
    int jg = tid >> 6;
    float a0 = 0.f, a1 = 0.f;
    for (int j = jg; j < S_TOT; j += 4) {
        unsigned int pv = *(const unsigned int*)(v + (size_t)j * C_DIM + h * DHEAD + ig);
        float p = logits[j];
        a0 += p * f_lo(pv);
        a1 += p * f_hi(pv);
    }
    part[jg][ig] = a0;
    part[jg][ig + 1] = a1;
    __syncthreads();
    if (tid < DHEAD) {
        float r = (part[0][tid] + part[1][tid] + part[2][tid] + part[3][tid]) * inv;
        o[(size_t)qi * C_DIM + h * DHEAD + tid] = f2bf(r);
    }
}

// ------ Residual + transpose (S,C) bf16 -> (C,S) out (dual dtype) -----
__global__ __launch_bounds__(256) void resid_t(const unsigned short* __restrict__ proj,
                                               const void* __restrict__ x,
                                               const int* __restrict__ flag,
                                               void* __restrict__ out) {
    int isf32 = *flag;
    __shared__ float tile[32][33];   // [s_local][c_local]
    int s0 = blockIdx.x * 32, c0 = blockIdx.y * 32;
    int tx = threadIdx.x, ty = threadIdx.y;   // (32,8)
    for (int r = 0; r < 4; ++r) {
        int sl = ty + 8 * r;
        tile[sl][tx] = bf2f(proj[(size_t)(s0 + sl) * C_DIM + (c0 + tx)]);
    }
    __syncthreads();
    for (int r = 0; r < 4; ++r) {
        int cl = ty + 8 * r;
        size_t idx = (size_t)(c0 + cl) * S_TOT + (s0 + tx);
        float val = ldin(x, idx, isf32) + tile[tx][cl];
        if (isf32) ((float*)out)[idx] = val;
        else       ((unsigned short*)out)[idx] = f2bf(val);
    }
}

extern "C" void kernel_launch(void* const* d_in, const int* in_sizes, int n_in,
                              void* d_out, int out_size, void* d_ws, size_t ws_size,
                              hipStream_t stream) {
    const void* x  = d_in[0];
    const void* Wq = d_in[1];
    const void* bq = d_in[2];
    const void* Wk = d_in[3];
    const void* bk = d_in[4];
    const void* Wv = d_in[5];
    const void* bv = d_in[6];
    const void* Wo = d_in[7];
    const void* bo = d_in[8];
    const void* gq = d_in[9];
    const void* gk = d_in[10];

    // ws budget ~35.8 MB: xn 11.9 | qb 11.9 | kb 11.9 | stats+flag ~0.03
    // vb lives in d_out (dead by the time resid_t writes). ob:=xn, proj:=qb.
    char* ws = (char*)d_ws;
    size_t off = 0;
    auto alloc = [&](size_t bytes) -> char* {
        char* p = ws + off;
        off += (bytes + 255) & ~(size_t)255;
        return p;
    };
    const size_t SC = (size_t)S_TOT * C_DIM;
    unsigned short* xn   = (unsigned short*)alloc(SC * 2);
    unsigned short* qb   = (unsigned short*)alloc(SC * 2);
    unsigned short* kb   = (unsigned short*)alloc(SC * 2);
    float* meanb         = (float*)alloc((size_t)S_TOT * 4);
    float* rstdb         = (float*)alloc((size_t)S_TOT * 4);
    int*   flag          = (int*)alloc(256);
    unsigned short* vb   = (unsigned short*)d_out;   // scratch inside d_out
    unsigned short* ob   = xn;   // alias (xn dead after V-GEMM)
    unsigned short* proj = qb;   // alias (qb dead after attn)

    dim3 t328(32, 8);
    dim3 tgrid(S_TOT / 32, C_DIM / 32);             // (121, 48)
    dim3 ggrid((S_TOT + BM - 1) / BM, C_DIM / BN);  // (61, 24)

    detect<<<1, 256, 0, stream>>>((const unsigned short*)x, flag);
    ln_stats<<<(S_TOT + 255) / 256, 256, 0, stream>>>(x, flag, meanb, rstdb);
    ln_norm_t<<<tgrid, t328, 0, stream>>>(x, flag, meanb, rstdb, xn);

    gemm_bias<<<ggrid, 256, 0, stream>>>(xn, Wq, bq, flag, qb);
    rms_rope<<<S_TOT, 256, 0, stream>>>(qb, gq, flag);

    gemm_bias<<<ggrid, 256, 0, stream>>>(xn, Wk, bk, flag, kb);
    rms_rope<<<S_TOT, 256, 0, stream>>>(kb, gk, flag);

    gemm_bias<<<ggrid, 256, 0, stream>>>(xn, Wv, bv, flag, vb);

    attn<<<NHEAD * S_TOT, 256, 0, stream>>>(qb, kb, vb, ob);

    gemm_bias<<<ggrid, 256, 0, stream>>>(ob, Wo, bo, flag, proj);
    resid_t<<<tgrid, t328, 0, stream>>>(proj, x, flag, d_out);
}

// Round 4
// 820.685 us; speedup vs baseline: 14.2132x; 14.2132x over previous
//
#include <hip/hip_runtime.h>

#define S_TOT 3872
#define C_DIM 1536
#define NHEAD 12
#define DHEAD 128
#define HALF  64
#define TT 8
#define HH 22
#define WW 22

typedef __bf16 bf16x8 __attribute__((ext_vector_type(8)));
typedef float  f32x4  __attribute__((ext_vector_type(4)));
typedef unsigned short u16x8 __attribute__((ext_vector_type(8)));

__device__ __forceinline__ float bf2f(unsigned short u) {
    unsigned int v = ((unsigned int)u) << 16;
    float f;
    __builtin_memcpy(&f, &v, 4);
    return f;
}
__device__ __forceinline__ unsigned short f2bf(float f) {
    unsigned int u;
    __builtin_memcpy(&u, &f, 4);
    unsigned int lsb = (u >> 16) & 1u;
    u += 0x7fffu + lsb;
    return (unsigned short)(u >> 16);
}
// dtype-agnostic external load: flag!=0 -> buffer is f32, else bf16
__device__ __forceinline__ float ldin(const void* p, size_t i, int isf32) {
    if (isf32) return ((const float*)p)[i];
    return bf2f(((const unsigned short*)p)[i]);
}

// ---------------- dtype detector: 1 block, writes flag ----------------
__global__ void detect(const unsigned short* __restrict__ x, int* __restrict__ flag) {
    __shared__ int cnt;
    if (threadIdx.x == 0) cnt = 0;
    __syncthreads();
    int c = 0;
    for (int i = 0; i < 8; ++i) {
        unsigned short u = x[threadIdx.x * 8 + i];
        int e = (u >> 7) & 0xFF;
        if (e >= 112 && e <= 143) c++;
    }
    atomicAdd(&cnt, c);
    __syncthreads();
    if (threadIdx.x == 0) *flag = (cnt >= 1900) ? 0 : 1;   // 1 => f32 inputs
}

// ---------------- LayerNorm stats: per column s over C ----------------
__global__ __launch_bounds__(256) void ln_stats(const void* __restrict__ x,
                                                const int* __restrict__ flag,
                                                float* __restrict__ meanb,
                                                float* __restrict__ rstdb) {
    int isf32 = *flag;
    int s = blockIdx.x * 256 + threadIdx.x;
    if (s >= S_TOT) return;
    float sum = 0.f, sumsq = 0.f;
    for (int c = 0; c < C_DIM; ++c) {
        float v = ldin(x, (size_t)c * S_TOT + s, isf32);
        sum += v; sumsq += v * v;
    }
    float m = sum * (1.0f / C_DIM);
    float var = sumsq * (1.0f / C_DIM) - m * m;
    meanb[s] = m;
    rstdb[s] = rsqrtf(var + 1e-6f);
}

// ------------- Normalize + transpose (C,S) -> (S,C) bf16 --------------
__global__ __launch_bounds__(256) void ln_norm_t(const void* __restrict__ x,
                                                 const int* __restrict__ flag,
                                                 const float* __restrict__ meanb,
                                                 const float* __restrict__ rstdb,
                                                 unsigned short* __restrict__ xn) {
    int isf32 = *flag;
    __shared__ float tile[32][33];   // [c_local][s_local]
    int s0 = blockIdx.x * 32, c0 = blockIdx.y * 32;
    int tx = threadIdx.x, ty = threadIdx.y;   // (32,8)
    for (int r = 0; r < 4; ++r) {
        int cl = ty + 8 * r;
        tile[cl][tx] = ldin(x, (size_t)(c0 + cl) * S_TOT + (s0 + tx), isf32);
    }
    __syncthreads();
    for (int r = 0; r < 4; ++r) {
        int sl = ty + 8 * r;
        int s = s0 + sl, c = c0 + tx;
        xn[(size_t)s * C_DIM + c] = f2bf((tile[tx][sl] - meanb[s]) * rstdb[s]);
    }
}

// --------------- MFMA GEMM: D(MxN) = A(MxK) * W(NxK)^T + bias, bf16 out
#define BM 64
#define BN 64
#define BK 32
#define LDA_P 40   // padded LDS stride (elements)

__global__ __launch_bounds__(256) void gemm_bias(const unsigned short* __restrict__ A,
                                                 const void* __restrict__ Bw,
                                                 const void* __restrict__ bias,
                                                 const int* __restrict__ flag,
                                                 unsigned short* __restrict__ D) {
    int isf32 = *flag;
    __shared__ __align__(16) unsigned short As[BM * LDA_P];
    __shared__ __align__(16) unsigned short Bs[BN * LDA_P];
    int m0 = blockIdx.x * BM;
    int n0 = blockIdx.y * BN;
    int tid = threadIdx.x;
    int wave = tid >> 6, lane = tid & 63;
    int srow = tid >> 2;            // 0..63
    int scol = (tid & 3) * 8;       // 0,8,16,24

    f32x4 acc0 = {0.f,0.f,0.f,0.f};
    f32x4 acc1 = {0.f,0.f,0.f,0.f};
    f32x4 acc2 = {0.f,0.f,0.f,0.f};
    f32x4 acc3 = {0.f,0.f,0.f,0.f};

    int ga = m0 + srow; if (ga >= S_TOT) ga = S_TOT - 1;
    int gb = n0 + srow;
    int ar = 16 * wave + (lane & 15);
    int koff = (lane >> 4) * 8;

    for (int k0 = 0; k0 < C_DIM; k0 += BK) {
        u16x8 av = *(const u16x8*)(A + (size_t)ga * C_DIM + k0 + scol);
        u16x8 bv;
        if (isf32) {
            const float* bp = (const float*)Bw + (size_t)gb * C_DIM + k0 + scol;
            float4 f0 = *(const float4*)(bp);
            float4 f1 = *(const float4*)(bp + 4);
            bv[0] = f2bf(f0.x); bv[1] = f2bf(f0.y); bv[2] = f2bf(f0.z); bv[3] = f2bf(f0.w);
            bv[4] = f2bf(f1.x); bv[5] = f2bf(f1.y); bv[6] = f2bf(f1.z); bv[7] = f2bf(f1.w);
        } else {
            bv = *(const u16x8*)((const unsigned short*)Bw + (size_t)gb * C_DIM + k0 + scol);
        }
        *(u16x8*)(&As[srow * LDA_P + scol]) = av;
        *(u16x8*)(&Bs[srow * LDA_P + scol]) = bv;
        __syncthreads();
        bf16x8 afrag = *(const bf16x8*)(&As[ar * LDA_P + koff]);
        bf16x8 b0 = *(const bf16x8*)(&Bs[( 0 + (lane & 15)) * LDA_P + koff]);
        bf16x8 b1 = *(const bf16x8*)(&Bs[(16 + (lane & 15)) * LDA_P + koff]);
        bf16x8 b2 = *(const bf16x8*)(&Bs[(32 + (lane & 15)) * LDA_P + koff]);
        bf16x8 b3 = *(const bf16x8*)(&Bs[(48 + (lane & 15)) * LDA_P + koff]);
        acc0 = __builtin_amdgcn_mfma_f32_16x16x32_bf16(afrag, b0, acc0, 0, 0, 0);
        acc1 = __builtin_amdgcn_mfma_f32_16x16x32_bf16(afrag, b1, acc1, 0, 0, 0);
        acc2 = __builtin_amdgcn_mfma_f32_16x16x32_bf16(afrag, b2, acc2, 0, 0, 0);
        acc3 = __builtin_amdgcn_mfma_f32_16x16x32_bf16(afrag, b3, acc3, 0, 0, 0);
        __syncthreads();
    }

    int row_base = m0 + 16 * wave + ((lane >> 4) * 4);
    int col = lane & 15;
    f32x4 accs[4] = {acc0, acc1, acc2, acc3};
    for (int nt = 0; nt < 4; ++nt) {
        int gn = n0 + 16 * nt + col;
        float bvf = ldin(bias, gn, isf32);
        for (int r = 0; r < 4; ++r) {
            int gm = row_base + r;
            if (gm < S_TOT) D[(size_t)gm * C_DIM + gn] = f2bf(accs[nt][r] + bvf);
        }
    }
}

// ---------- RMSNorm (full C) + RoPE, IN-PLACE on bf16 (S,C) -----------
__global__ __launch_bounds__(256) void rms_rope(unsigned short* __restrict__ buf,
                                                const void* __restrict__ g,
                                                const int* __restrict__ flag) {
    int isf32 = *flag;
    int s = blockIdx.x;
    unsigned short* row = buf + (size_t)s * C_DIM;
    int tid = threadIdx.x;
    float ss = 0.f;
    for (int i = 0; i < 6; ++i) {
        float v = bf2f(row[tid + 256 * i]);
        ss += v * v;
    }
    for (int off = 32; off; off >>= 1) ss += __shfl_down(ss, off, 64);
    __shared__ float wsum[4];
    __shared__ float scale_sh;
    if ((tid & 63) == 0) wsum[tid >> 6] = ss;
    __syncthreads();
    if (tid == 0) {
        float tot = wsum[0] + wsum[1] + wsum[2] + wsum[3];
        scale_sh = rsqrtf(tot * (1.0f / C_DIM) + 1e-6f);
    }
    __syncthreads();
    float scale = scale_sh;

    int t  = s / (HH * WW);
    int rm = s % (HH * WW);
    int hh = rm / WW, ww = rm % WW;

    float e[3][2];
    int cols[3];
    for (int i = 0; i < 3; ++i) {
        int p = tid + 256 * i;        // pair index 0..767
        int j = p & 63;
        int col0 = (p >> 6) * DHEAD + 2 * j;
        cols[i] = col0;
        float e0 = bf2f(row[col0])     * scale * ldin(g, col0, isf32);
        float e1 = bf2f(row[col0 + 1]) * scale * ldin(g, col0 + 1, isf32);
        float pos, fr;
        if (j < 22)       { pos = (float)t;  fr = (float)j        * (1.0f / 22.0f); }
        else if (j < 43)  { pos = (float)hh; fr = (float)(j - 22) * (1.0f / 21.0f); }
        else              { pos = (float)ww; fr = (float)(j - 43) * (1.0f / 21.0f); }
        float ang = pos * expf(fr * -9.210340371976184f);   // *10000^-fr
        float c = cosf(ang), sn = sinf(ang);
        e[i][0] = e0 * c - e1 * sn;
        e[i][1] = e0 * sn + e1 * c;
    }
    for (int i = 0; i < 3; ++i) {
        row[cols[i]]     = f2bf(e[i][0]);
        row[cols[i] + 1] = f2bf(e[i][1]);
    }
}

// ------------- MFMA flash attention: block = (head, 64-row Q tile) ----
// LDS: K tile row-layout (pad 136), V^T XOR-swizzled (stride 72),
// per-wave P buffer (stride 72). 45 KB -> 3 blocks/CU.
__global__ __launch_bounds__(256) void attn_mfma(const unsigned short* __restrict__ q,
                                                 const unsigned short* __restrict__ k,
                                                 const unsigned short* __restrict__ v,
                                                 unsigned short* __restrict__ o) {
    constexpr int KT  = 64;
    constexpr int NKT = (S_TOT + KT - 1) / KT;  // 61
    constexpr int KP  = 136;
    constexpr int VP  = 72;
    constexpr int PP  = 72;
    __shared__ __align__(16) unsigned short Ks[64 * KP];
    __shared__ __align__(16) unsigned short VTs[DHEAD * VP];
    __shared__ __align__(16) unsigned short Ps[4][16 * PP];

    int h  = blockIdx.x / 61;
    int qt = blockIdx.x % 61;
    int q0 = qt * 64;
    int tid = threadIdx.x;
    int wave = tid >> 6, lane = tid & 63;
    int lm = lane & 15, lq = lane >> 4;

    // Q fragments (A-layout): row lm, k = kc*32 + lq*8 + j
    bf16x8 qf[4];
    {
        int qr = q0 + wave * 16 + lm; if (qr >= S_TOT) qr = S_TOT - 1;
        const unsigned short* qp = q + (size_t)qr * C_DIM + h * DHEAD + lq * 8;
        #pragma unroll
        for (int kc = 0; kc < 4; ++kc) qf[kc] = *(const bf16x8*)(qp + kc * 32);
    }

    f32x4 oacc[8];
    #pragma unroll
    for (int i = 0; i < 8; ++i) oacc[i] = (f32x4){0.f, 0.f, 0.f, 0.f};
    float m_run[4], l_run[4];
    #pragma unroll
    for (int r = 0; r < 4; ++r) { m_run[r] = -INFINITY; l_run[r] = 0.f; }

    int srow = tid >> 2;             // K staging row 0..63
    int scol = (tid & 3) * 32;       // K staging col
    int vd0  = (tid & 15) * 8;       // V^T staging d-chunk
    int vrb  = (tid >> 4) * 2;       // V^T staging row-pair base

    const float scale = 0.08838834764831845f;  // 1/sqrt(128)

    for (int kt = 0; kt < NKT; ++kt) {
        int k0 = kt * KT;
        __syncthreads();
        // stage K rows
        {
            int jg = k0 + srow; if (jg >= S_TOT) jg = S_TOT - 1;
            const unsigned short* kr = k + (size_t)jg * C_DIM + h * DHEAD + scol;
            #pragma unroll
            for (int c = 0; c < 4; ++c)
                *(u16x8*)(&Ks[srow * KP + scol + c * 8]) = *(const u16x8*)(kr + c * 8);
        }
        // stage V^T (swizzled chunk = (key>>3) ^ ((d>>3)&7)); dword = 2 keys
        #pragma unroll
        for (int half = 0; half < 2; ++half) {
            int r0 = vrb + half * 32;   // even
            int jg0 = k0 + r0;     if (jg0 >= S_TOT) jg0 = S_TOT - 1;
            int jg1 = k0 + r0 + 1; if (jg1 >= S_TOT) jg1 = S_TOT - 1;
            u16x8 va = *(const u16x8*)(v + (size_t)jg0 * C_DIM + h * DHEAD + vd0);
            u16x8 vb = *(const u16x8*)(v + (size_t)jg1 * C_DIM + h * DHEAD + vd0);
            #pragma unroll
            for (int e = 0; e < 8; ++e) {
                int d = vd0 + e;
                int chunk = (r0 >> 3) ^ ((d >> 3) & 7);
                unsigned int pack = (unsigned int)va[e] | ((unsigned int)vb[e] << 16);
                *(unsigned int*)(&VTs[d * VP + (chunk << 3) + (r0 & 7)]) = pack;
            }
        }
        __syncthreads();

        // QK^T: S[16 x 64] per wave
        f32x4 sacc[4];
        #pragma unroll
        for (int nt = 0; nt < 4; ++nt) sacc[nt] = (f32x4){0.f, 0.f, 0.f, 0.f};
        #pragma unroll
        for (int kc = 0; kc < 4; ++kc) {
            int ko = kc * 32 + lq * 8;
            #pragma unroll
            for (int nt = 0; nt < 4; ++nt) {
                bf16x8 bf = *(const bf16x8*)(&Ks[(nt * 16 + lm) * KP + ko]);
                sacc[nt] = __builtin_amdgcn_mfma_f32_16x16x32_bf16(qf[kc], bf, sacc[nt], 0, 0, 0);
            }
        }
        // scale + key mask (last tile only)
        bool lastt = (kt == NKT - 1);
        #pragma unroll
        for (int nt = 0; nt < 4; ++nt) {
            bool ok = !lastt || (k0 + nt * 16 + lm < S_TOT);
            #pragma unroll
            for (int r = 0; r < 4; ++r)
                sacc[nt][r] = ok ? sacc[nt][r] * scale : -INFINITY;
        }
        // online softmax (C-layout rows: row = lq*4 + r, spread over 16 lanes)
        float alpha[4];
        #pragma unroll
        for (int r = 0; r < 4; ++r) {
            float rmax = fmaxf(fmaxf(sacc[0][r], sacc[1][r]), fmaxf(sacc[2][r], sacc[3][r]));
            #pragma unroll
            for (int off = 1; off < 16; off <<= 1)
                rmax = fmaxf(rmax, __shfl_xor(rmax, off, 64));
            float mn = fmaxf(m_run[r], rmax);
            alpha[r] = __expf(m_run[r] - mn);
            float rs = 0.f;
            #pragma unroll
            for (int nt = 0; nt < 4; ++nt) {
                float p = __expf(sacc[nt][r] - mn);
                sacc[nt][r] = p;
                rs += p;
            }
            #pragma unroll
            for (int off = 1; off < 16; off <<= 1)
                rs += __shfl_xor(rs, off, 64);
            l_run[r] = l_run[r] * alpha[r] + rs;
            m_run[r] = mn;
        }
        // P -> per-wave LDS (bf16, A-layout source)
        #pragma unroll
        for (int nt = 0; nt < 4; ++nt)
            #pragma unroll
            for (int r = 0; r < 4; ++r)
                Ps[wave][(lq * 4 + r) * PP + nt * 16 + lm] = f2bf(sacc[nt][r]);
        // rescale O
        #pragma unroll
        for (int i = 0; i < 8; ++i)
            #pragma unroll
            for (int r = 0; r < 4; ++r) oacc[i][r] *= alpha[r];
        __syncthreads();
        // PV: O[16 x 128] += P[16 x 64] * V[64 x 128]
        #pragma unroll
        for (int kc = 0; kc < 2; ++kc) {
            int ko = kc * 32 + lq * 8;
            bf16x8 pf = *(const bf16x8*)(&Ps[wave][lm * PP + ko]);
            #pragma unroll
            for (int nt = 0; nt < 8; ++nt) {
                int d = nt * 16 + lm;
                int chunk = (ko >> 3) ^ ((d >> 3) & 7);
                bf16x8 vf = *(const bf16x8*)(&VTs[d * VP + (chunk << 3)]);
                oacc[nt] = __builtin_amdgcn_mfma_f32_16x16x32_bf16(pf, vf, oacc[nt], 0, 0, 0);
            }
        }
    }
    // epilogue: O /= l, store
    #pragma unroll
    for (int r = 0; r < 4; ++r) {
        int qr = q0 + wave * 16 + lq * 4 + r;
        if (qr < S_TOT) {
            float inv = 1.0f / l_run[r];
            #pragma unroll
            for (int nt = 0; nt < 8; ++nt)
                o[(size_t)qr * C_DIM + h * DHEAD + nt * 16 + lm] = f2bf(oacc[nt][r] * inv);
        }
    }
}

// ------ Residual + transpose (S,C) bf16 -> (C,S) out (dual dtype) -----
__global__ __launch_bounds__(256) void resid_t(const unsigned short* __restrict__ proj,
                                               const void* __restrict__ x,
                                               const int* __restrict__ flag,
                                               void* __restrict__ out) {
    int isf32 = *flag;
    __shared__ float tile[32][33];   // [s_local][c_local]
    int s0 = blockIdx.x * 32, c0 = blockIdx.y * 32;
    int tx = threadIdx.x, ty = threadIdx.y;   // (32,8)
    for (int r = 0; r < 4; ++r) {
        int sl = ty + 8 * r;
        tile[sl][tx] = bf2f(proj[(size_t)(s0 + sl) * C_DIM + (c0 + tx)]);
    }
    __syncthreads();
    for (int r = 0; r < 4; ++r) {
        int cl = ty + 8 * r;
        size_t idx = (size_t)(c0 + cl) * S_TOT + (s0 + tx);
        float val = ldin(x, idx, isf32) + tile[tx][cl];
        if (isf32) ((float*)out)[idx] = val;
        else       ((unsigned short*)out)[idx] = f2bf(val);
    }
}

extern "C" void kernel_launch(void* const* d_in, const int* in_sizes, int n_in,
                              void* d_out, int out_size, void* d_ws, size_t ws_size,
                              hipStream_t stream) {
    const void* x  = d_in[0];
    const void* Wq = d_in[1];
    const void* bq = d_in[2];
    const void* Wk = d_in[3];
    const void* bk = d_in[4];
    const void* Wv = d_in[5];
    const void* bv = d_in[6];
    const void* Wo = d_in[7];
    const void* bo = d_in[8];
    const void* gq = d_in[9];
    const void* gk = d_in[10];

    char* ws = (char*)d_ws;
    size_t off = 0;
    auto alloc = [&](size_t bytes) -> char* {
        char* p = ws + off;
        off += (bytes + 255) & ~(size_t)255;
        return p;
    };
    const size_t SC = (size_t)S_TOT * C_DIM;
    unsigned short* xn   = (unsigned short*)alloc(SC * 2);
    unsigned short* qb   = (unsigned short*)alloc(SC * 2);
    unsigned short* kb   = (unsigned short*)alloc(SC * 2);
    float* meanb         = (float*)alloc((size_t)S_TOT * 4);
    float* rstdb         = (float*)alloc((size_t)S_TOT * 4);
    int*   flag          = (int*)alloc(256);
    unsigned short* vb   = (unsigned short*)d_out;   // scratch inside d_out
    unsigned short* ob   = xn;   // alias (xn dead after V-GEMM)
    unsigned short* proj = qb;   // alias (qb dead after attn)

    dim3 t328(32, 8);
    dim3 tgrid(S_TOT / 32, C_DIM / 32);             // (121, 48)
    dim3 ggrid((S_TOT + BM - 1) / BM, C_DIM / BN);  // (61, 24)

    detect<<<1, 256, 0, stream>>>((const unsigned short*)x, flag);
    ln_stats<<<(S_TOT + 255) / 256, 256, 0, stream>>>(x, flag, meanb, rstdb);
    ln_norm_t<<<tgrid, t328, 0, stream>>>(x, flag, meanb, rstdb, xn);

    gemm_bias<<<ggrid, 256, 0, stream>>>(xn, Wq, bq, flag, qb);
    rms_rope<<<S_TOT, 256, 0, stream>>>(qb, gq, flag);

    gemm_bias<<<ggrid, 256, 0, stream>>>(xn, Wk, bk, flag, kb);
    rms_rope<<<S_TOT, 256, 0, stream>>>(kb, gk, flag);

    gemm_bias<<<ggrid, 256, 0, stream>>>(xn, Wv, bv, flag, vb);

    attn_mfma<<<NHEAD * 61, 256, 0, stream>>>(qb, kb, vb, ob);

    gemm_bias<<<ggrid, 256, 0, stream>>>(ob, Wo, bo, flag, proj);
    resid_t<<<tgrid, t328, 0, stream>>>(proj, x, flag, d_out);
}

// Round 5
// 813.718 us; speedup vs baseline: 14.3349x; 1.0086x over previous
//
#include <hip/hip_runtime.h>

#define S_TOT 3872
#define C_DIM 1536
#define NHEAD 12
#define DHEAD 128
#define TT 8
#define HH 22
#define WW 22
#define NKT 61          // ceil(3872/64): both K-tiles and Q-tiles

typedef __bf16 bf16x8 __attribute__((ext_vector_type(8)));
typedef float  f32x4  __attribute__((ext_vector_type(4)));
typedef unsigned short u16x8 __attribute__((ext_vector_type(8)));

__device__ __forceinline__ float bf2f(unsigned short u) {
    unsigned int v = ((unsigned int)u) << 16;
    float f; __builtin_memcpy(&f, &v, 4); return f;
}
__device__ __forceinline__ unsigned short f2bf(float f) {
    unsigned int u; __builtin_memcpy(&u, &f, 4);
    u += 0x7fffu + ((u >> 16) & 1u);
    return (unsigned short)(u >> 16);
}
__device__ __forceinline__ float ldin(const void* p, size_t i, int isf32) {
    if (isf32) return ((const float*)p)[i];
    return bf2f(((const unsigned short*)p)[i]);
}
__device__ __forceinline__ float fexp2(float x) {
#if __has_builtin(__builtin_amdgcn_exp2f)
    return __builtin_amdgcn_exp2f(x);
#else
    return exp2f(x);
#endif
}
// async global->LDS, 16B per lane; LDS dest = wave-uniform base + lane*16
__device__ __forceinline__ void async16(const void* g, void* l) {
    __builtin_amdgcn_global_load_lds(
        (const __attribute__((address_space(1))) unsigned int*)g,
        (__attribute__((address_space(3))) unsigned int*)l, 16, 0, 0);
}

// ---------------- dtype detector: 1 block, writes flag ----------------
__global__ void detect(const unsigned short* __restrict__ x, int* __restrict__ flag) {
    __shared__ int cnt;
    if (threadIdx.x == 0) cnt = 0;
    __syncthreads();
    int c = 0;
    for (int i = 0; i < 8; ++i) {
        unsigned short u = x[threadIdx.x * 8 + i];
        int e = (u >> 7) & 0xFF;
        if (e >= 112 && e <= 143) c++;
    }
    atomicAdd(&cnt, c);
    __syncthreads();
    if (threadIdx.x == 0) *flag = (cnt >= 1900) ? 0 : 1;   // 1 => f32 inputs
}

// -------- weight matrix -> bf16 (2.36M elems, 8/thread, grid 1152) ----
__global__ __launch_bounds__(256) void wconv_mat(const void* __restrict__ src,
                                                 const int* __restrict__ flag,
                                                 unsigned short* __restrict__ dst) {
    size_t i = ((size_t)blockIdx.x * 256 + threadIdx.x) * 8;
    if (*flag) {
        const float* s = (const float*)src + i;
        float4 a = *(const float4*)s, b = *(const float4*)(s + 4);
        u16x8 o;
        o[0]=f2bf(a.x); o[1]=f2bf(a.y); o[2]=f2bf(a.z); o[3]=f2bf(a.w);
        o[4]=f2bf(b.x); o[5]=f2bf(b.y); o[6]=f2bf(b.z); o[7]=f2bf(b.w);
        *(u16x8*)(dst + i) = o;
    } else {
        *(u16x8*)(dst + i) = *(const u16x8*)((const unsigned short*)src + i);
    }
}

// ------- 6 small vectors (bq,bk,bv,bo,gq,gk) -> bf16, grid 6 ----------
__global__ void wconv_vec(const void* p0, const void* p1, const void* p2,
                          const void* p3, const void* p4, const void* p5,
                          const int* __restrict__ flag, unsigned short* __restrict__ dst) {
    const void* ps[6] = {p0, p1, p2, p3, p4, p5};
    int v = blockIdx.x;
    int isf32 = *flag;
    for (int j = threadIdx.x; j < C_DIM; j += 256)
        dst[v * C_DIM + j] = f2bf(ldin(ps[v], j, isf32));
}

// ---------------- LayerNorm stats: grid 61, block (64 s x 4 cg) -------
__global__ __launch_bounds__(256) void ln_stats(const void* __restrict__ x,
                                                const int* __restrict__ flag,
                                                float* __restrict__ meanb,
                                                float* __restrict__ rstdb) {
    int isf32 = *flag;
    int sl = threadIdx.x & 63, cg = threadIdx.x >> 6;
    int s = blockIdx.x * 64 + sl;
    float sum = 0.f, sumsq = 0.f;
    if (s < S_TOT) {
        for (int c = cg; c < C_DIM; c += 4) {
            float v = ldin(x, (size_t)c * S_TOT + s, isf32);
            sum += v; sumsq += v * v;
        }
    }
    __shared__ float r0[4][64], r1[4][64];
    r0[cg][sl] = sum; r1[cg][sl] = sumsq;
    __syncthreads();
    if (cg == 0 && s < S_TOT) {
        float st = r0[0][sl] + r0[1][sl] + r0[2][sl] + r0[3][sl];
        float sq = r1[0][sl] + r1[1][sl] + r1[2][sl] + r1[3][sl];
        float m = st * (1.0f / C_DIM);
        float var = sq * (1.0f / C_DIM) - m * m;
        meanb[s] = m;
        rstdb[s] = rsqrtf(var + 1e-6f);
    }
}

// ------------- Normalize + transpose (C,S) -> (S,C) bf16 --------------
__global__ __launch_bounds__(256) void ln_norm_t(const void* __restrict__ x,
                                                 const int* __restrict__ flag,
                                                 const float* __restrict__ meanb,
                                                 const float* __restrict__ rstdb,
                                                 unsigned short* __restrict__ xn) {
    int isf32 = *flag;
    __shared__ float tile[32][33];
    int s0 = blockIdx.x * 32, c0 = blockIdx.y * 32;
    int tx = threadIdx.x, ty = threadIdx.y;   // (32,8)
    for (int r = 0; r < 4; ++r) {
        int cl = ty + 8 * r;
        tile[cl][tx] = ldin(x, (size_t)(c0 + cl) * S_TOT + (s0 + tx), isf32);
    }
    __syncthreads();
    for (int r = 0; r < 4; ++r) {
        int sl = ty + 8 * r;
        int s = s0 + sl, c = c0 + tx;
        xn[(size_t)s * C_DIM + c] = f2bf((tile[tx][sl] - meanb[s]) * rstdb[s]);
    }
}

// ------- MFMA GEMM 128x128, BK=32, global_load_lds staging ------------
// D = A(MxK) * W(NxK)^T + bias. transV=0: D[s][C] bf16. transV=1: Vt[n][s].
__global__ __launch_bounds__(256) void gemm128(const unsigned short* __restrict__ A,
                                               const unsigned short* __restrict__ W,
                                               const unsigned short* __restrict__ bias,
                                               unsigned short* __restrict__ D,
                                               int transV) {
    __shared__ __align__(16) unsigned short As[4096];  // [128][32] packed
    __shared__ __align__(16) unsigned short Bs[4096];
    int m0 = blockIdx.x * 128, n0 = blockIdx.y * 128;
    int tid = threadIdx.x;
    int wave = tid >> 6, lane = tid & 63;
    int lm = lane & 15, lq = lane >> 4;
    int wm = wave & 1, wn = wave >> 1;
    int srow = lane >> 2, scol = (lane & 3) * 8;   // DMA lane pattern

    f32x4 acc[4][4];
    #pragma unroll
    for (int a = 0; a < 4; ++a)
        #pragma unroll
        for (int b = 0; b < 4; ++b) acc[a][b] = (f32x4){0.f, 0.f, 0.f, 0.f};

    for (int k0 = 0; k0 < C_DIM; k0 += 32) {
        __syncthreads();
        #pragma unroll
        for (int t = 0; t < 2; ++t) {
            int g = wave * 2 + t;
            int am = m0 + g * 16 + srow; if (am > S_TOT - 1) am = S_TOT - 1;
            async16(A + (size_t)am * C_DIM + k0 + scol, (char*)As + g * 1024);
            int bn = n0 + g * 16 + srow;
            async16(W + (size_t)bn * C_DIM + k0 + scol, (char*)Bs + g * 1024);
        }
        __syncthreads();
        bf16x8 af[4], bf[4];
        #pragma unroll
        for (int mb = 0; mb < 4; ++mb)
            af[mb] = *(const bf16x8*)((const char*)As + (wm * 64 + mb * 16 + lm) * 64 + lq * 16);
        #pragma unroll
        for (int nb = 0; nb < 4; ++nb)
            bf[nb] = *(const bf16x8*)((const char*)Bs + (wn * 64 + nb * 16 + lm) * 64 + lq * 16);
        #pragma unroll
        for (int mb = 0; mb < 4; ++mb)
            #pragma unroll
            for (int nb = 0; nb < 4; ++nb)
                acc[mb][nb] = __builtin_amdgcn_mfma_f32_16x16x32_bf16(af[mb], bf[nb], acc[mb][nb], 0, 0, 0);
    }

    if (!transV) {
        #pragma unroll
        for (int mb = 0; mb < 4; ++mb)
            #pragma unroll
            for (int nb = 0; nb < 4; ++nb) {
                int gn = n0 + wn * 64 + nb * 16 + lm;
                float bv = bf2f(bias[gn]);
                #pragma unroll
                for (int r = 0; r < 4; ++r) {
                    int gm = m0 + wm * 64 + mb * 16 + lq * 4 + r;
                    if (gm < S_TOT) D[(size_t)gm * C_DIM + gn] = f2bf(acc[mb][nb][r] + bv);
                }
            }
    } else {
        #pragma unroll
        for (int mb = 0; mb < 4; ++mb) {
            int gm0 = m0 + wm * 64 + mb * 16 + lq * 4;
            if (gm0 >= S_TOT) continue;           // S_TOT % 4 == 0: all-or-nothing
            #pragma unroll
            for (int nb = 0; nb < 4; ++nb) {
                int gn = n0 + wn * 64 + nb * 16 + lm;
                float bv = bf2f(bias[gn]);
                ushort4 pk;
                pk.x = f2bf(acc[mb][nb][0] + bv);
                pk.y = f2bf(acc[mb][nb][1] + bv);
                pk.z = f2bf(acc[mb][nb][2] + bv);
                pk.w = f2bf(acc[mb][nb][3] + bv);
                *(ushort4*)(D + (size_t)gn * S_TOT + gm0) = pk;
            }
        }
    }
}

// ---------- RMSNorm + RoPE, in-place; premul folds attn scale ---------
__global__ __launch_bounds__(256) void rms_rope(unsigned short* __restrict__ buf,
                                                const unsigned short* __restrict__ g,
                                                float premul) {
    int s = blockIdx.x;
    unsigned short* row = buf + (size_t)s * C_DIM;
    int tid = threadIdx.x;
    float ss = 0.f;
    for (int i = 0; i < 6; ++i) {
        float v = bf2f(row[tid + 256 * i]);
        ss += v * v;
    }
    for (int off = 32; off; off >>= 1) ss += __shfl_down(ss, off, 64);
    __shared__ float wsum[4];
    __shared__ float scale_sh;
    if ((tid & 63) == 0) wsum[tid >> 6] = ss;
    __syncthreads();
    if (tid == 0) {
        float tot = wsum[0] + wsum[1] + wsum[2] + wsum[3];
        scale_sh = rsqrtf(tot * (1.0f / C_DIM) + 1e-6f) * premul;
    }
    __syncthreads();
    float scale = scale_sh;

    int t  = s / (HH * WW);
    int rm = s % (HH * WW);
    int hh = rm / WW, ww = rm % WW;

    float e[3][2];
    int cols[3];
    for (int i = 0; i < 3; ++i) {
        int p = tid + 256 * i;
        int j = p & 63;
        int col0 = (p >> 6) * DHEAD + 2 * j;
        cols[i] = col0;
        float e0 = bf2f(row[col0])     * scale * bf2f(g[col0]);
        float e1 = bf2f(row[col0 + 1]) * scale * bf2f(g[col0 + 1]);
        float pos, fr;
        if (j < 22)       { pos = (float)t;  fr = (float)j        * (1.0f / 22.0f); }
        else if (j < 43)  { pos = (float)hh; fr = (float)(j - 22) * (1.0f / 21.0f); }
        else              { pos = (float)ww; fr = (float)(j - 43) * (1.0f / 21.0f); }
        float ang = pos * expf(fr * -9.210340371976184f);
        float c = cosf(ang), sn = sinf(ang);
        e[i][0] = e0 * c - e1 * sn;
        e[i][1] = e0 * sn + e1 * c;
    }
    for (int i = 0; i < 3; ++i) {
        row[cols[i]]     = f2bf(e[i][0]);
        row[cols[i] + 1] = f2bf(e[i][1]);
    }
}

// ---------------- MFMA flash attention v2 -----------------------------
// K: DMA double-buffer, 4-row/1056B groups. V: reg prefetch from Vt ->
// XOR-swizzled LDS. Ps: PP=64, chunk^(row>>1) swizzle. Q pre-scaled by
// scale*log2e -> base-2 softmax. LDS 58.4 KB -> 2 blocks/CU.
__global__ __launch_bounds__(256) void attn_mfma(const unsigned short* __restrict__ q,
                                                 const unsigned short* __restrict__ kp,
                                                 const unsigned short* __restrict__ vt,
                                                 unsigned short* __restrict__ o) {
    __shared__ __align__(16) unsigned char KsB[2][16896];   // 16 groups * 1056
    __shared__ __align__(16) unsigned short Vs[128 * 64];   // [d][64keys] XOR-swizzled
    __shared__ __align__(16) unsigned short Ps[4][1024];    // per-wave P, PP=64 swizzled

    int h  = blockIdx.x / NKT;
    int qt = blockIdx.x % NKT;
    int q0 = qt * 64;
    int tid = threadIdx.x;
    int wave = tid >> 6, lane = tid & 63;
    int lm = lane & 15, lq = lane >> 4;

    // Q fragments (A-layout), q already scaled by 1/sqrt(d)*log2(e)
    bf16x8 qf[4];
    {
        int qr = q0 + wave * 16 + lm; if (qr >= S_TOT) qr = S_TOT - 1;
        const unsigned short* qptr = q + (size_t)qr * C_DIM + h * DHEAD + lq * 8;
        #pragma unroll
        for (int kc = 0; kc < 4; ++kc) qf[kc] = *(const bf16x8*)(qptr + kc * 32);
    }

    // K-DMA lane constants
    int kg_row = lane >> 4;
    size_t kcol = (size_t)(h * DHEAD + (lane & 15) * 8);
    // V prefetch lane constants
    int vd  = tid >> 1;
    int vkh = (tid & 1) * 32;
    const unsigned short* vrow = vt + (size_t)(h * DHEAD + vd) * S_TOT;
    int vwaddr[4];
    #pragma unroll
    for (int c = 0; c < 4; ++c)
        vwaddr[c] = vd * 128 + (((((tid & 1) * 4 + c) ^ (vd & 7)) & 7) << 4);  // bytes
    // QK LDS read offsets (bytes)
    int ksoff[4], kqoff[4];
    #pragma unroll
    for (int nt = 0; nt < 4; ++nt) ksoff[nt] = (nt * 4 + (lm >> 2)) * 1056 + (lm & 3) * 256;
    #pragma unroll
    for (int kc = 0; kc < 4; ++kc) kqoff[kc] = (kc * 4 + lq) * 16;
    // PV Vs read offsets (bytes)
    int vcoff[2];
    #pragma unroll
    for (int kc = 0; kc < 2; ++kc) vcoff[kc] = ((((kc * 4 + lq) ^ (lm & 7)) & 7) << 4);

    f32x4 oacc[8];
    #pragma unroll
    for (int i = 0; i < 8; ++i) oacc[i] = (f32x4){0.f, 0.f, 0.f, 0.f};
    float m_run[4], l_run[4];
    #pragma unroll
    for (int r = 0; r < 4; ++r) { m_run[r] = -INFINITY; l_run[r] = 0.f; }

    uint4 vreg[4];
    // prolog: prefetch tile 0
    #pragma unroll
    for (int c = 0; c < 4; ++c) {
        int key = vkh + c * 8; if (key > S_TOT - 8) key = S_TOT - 8;
        vreg[c] = *(const uint4*)(vrow + key);
    }
    #pragma unroll
    for (int t = 0; t < 4; ++t) {
        int g = wave * 4 + t;
        int grow = 4 * g + kg_row; if (grow > S_TOT - 1) grow = S_TOT - 1;
        async16(kp + (size_t)grow * C_DIM + kcol, &KsB[0][g * 1056]);
    }

    for (int kt = 0; kt < NKT; ++kt) {
        int cur = kt & 1;
        __syncthreads();   // sync A: KsB[cur] + vreg landed; prev PV done
        // write V tile to LDS
        #pragma unroll
        for (int c = 0; c < 4; ++c)
            *(uint4*)((char*)Vs + vwaddr[c]) = vreg[c];
        // QK^T
        f32x4 sacc[4];
        #pragma unroll
        for (int nt = 0; nt < 4; ++nt) sacc[nt] = (f32x4){0.f, 0.f, 0.f, 0.f};
        const char* ksb = (const char*)KsB[cur];
        #pragma unroll
        for (int kc = 0; kc < 4; ++kc)
            #pragma unroll
            for (int nt = 0; nt < 4; ++nt) {
                bf16x8 kf = *(const bf16x8*)(ksb + ksoff[nt] + kqoff[kc]);
                sacc[nt] = __builtin_amdgcn_mfma_f32_16x16x32_bf16(qf[kc], kf, sacc[nt], 0, 0, 0);
            }
        __syncthreads();   // sync B: Vs visible to all waves
        // prefetch tile kt+1 (in flight over softmax+PV)
        if (kt < NKT - 1) {
            int k0n = (kt + 1) * 64;
            #pragma unroll
            for (int t = 0; t < 4; ++t) {
                int g = wave * 4 + t;
                int grow = k0n + 4 * g + kg_row; if (grow > S_TOT - 1) grow = S_TOT - 1;
                async16(kp + (size_t)grow * C_DIM + kcol, &KsB[1 - cur][g * 1056]);
            }
            #pragma unroll
            for (int c = 0; c < 4; ++c) {
                int key = k0n + vkh + c * 8; if (key > S_TOT - 8) key = S_TOT - 8;
                vreg[c] = *(const uint4*)(vrow + key);
            }
        }
        // mask tail keys (last tile only)
        if (kt == NKT - 1) {
            #pragma unroll
            for (int nt = 0; nt < 4; ++nt) {
                bool ok = (kt * 64 + nt * 16 + lm) < S_TOT;
                #pragma unroll
                for (int r = 0; r < 4; ++r)
                    if (!ok) sacc[nt][r] = -INFINITY;
            }
        }
        // online softmax, base-2
        float alpha[4];
        #pragma unroll
        for (int r = 0; r < 4; ++r) {
            float rmax = fmaxf(fmaxf(sacc[0][r], sacc[1][r]), fmaxf(sacc[2][r], sacc[3][r]));
            #pragma unroll
            for (int off = 1; off < 16; off <<= 1)
                rmax = fmaxf(rmax, __shfl_xor(rmax, off, 64));
            float mn = fmaxf(m_run[r], rmax);
            alpha[r] = fexp2(m_run[r] - mn);
            float rs = 0.f;
            #pragma unroll
            for (int nt = 0; nt < 4; ++nt) {
                float p = fexp2(sacc[nt][r] - mn);
                sacc[nt][r] = p;
                rs += p;
            }
            #pragma unroll
            for (int off = 1; off < 16; off <<= 1)
                rs += __shfl_xor(rs, off, 64);
            l_run[r] = l_run[r] * alpha[r] + rs;
            m_run[r] = mn;
        }
        // P -> per-wave LDS (swizzled)
        #pragma unroll
        for (int nt = 0; nt < 4; ++nt)
            #pragma unroll
            for (int r = 0; r < 4; ++r) {
                int row = lq * 4 + r;
                int ch = ((nt * 2 + (lm >> 3)) ^ (row >> 1)) & 7;
                Ps[wave][row * 64 + (ch << 3) + (lm & 7)] = f2bf(sacc[nt][r]);
            }
        // rescale O
        #pragma unroll
        for (int i = 0; i < 8; ++i)
            #pragma unroll
            for (int r = 0; r < 4; ++r) oacc[i][r] *= alpha[r];
        // PV (Ps is wave-private: same-wave LDS ordering, no barrier)
        #pragma unroll
        for (int kc = 0; kc < 2; ++kc) {
            bf16x8 pf = *(const bf16x8*)(&Ps[wave][lm * 64 + (((((kc * 4 + lq) ^ (lm >> 1)) & 7)) << 3)]);
            #pragma unroll
            for (int nt = 0; nt < 8; ++nt) {
                bf16x8 vf = *(const bf16x8*)((const char*)Vs + (nt * 16 + lm) * 128 + vcoff[kc]);
                oacc[nt] = __builtin_amdgcn_mfma_f32_16x16x32_bf16(pf, vf, oacc[nt], 0, 0, 0);
            }
        }
    }
    // epilogue
    #pragma unroll
    for (int r = 0; r < 4; ++r) {
        int qr = q0 + wave * 16 + lq * 4 + r;
        if (qr < S_TOT) {
            float inv = 1.0f / l_run[r];
            #pragma unroll
            for (int nt = 0; nt < 8; ++nt)
                o[(size_t)qr * C_DIM + h * DHEAD + nt * 16 + lm] = f2bf(oacc[nt][r] * inv);
        }
    }
}

// ------ Residual + transpose (S,C) bf16 -> (C,S) out (dual dtype) -----
__global__ __launch_bounds__(256) void resid_t(const unsigned short* __restrict__ proj,
                                               const void* __restrict__ x,
                                               const int* __restrict__ flag,
                                               void* __restrict__ out) {
    int isf32 = *flag;
    __shared__ float tile[32][33];
    int s0 = blockIdx.x * 32, c0 = blockIdx.y * 32;
    int tx = threadIdx.x, ty = threadIdx.y;   // (32,8)
    for (int r = 0; r < 4; ++r) {
        int sl = ty + 8 * r;
        tile[sl][tx] = bf2f(proj[(size_t)(s0 + sl) * C_DIM + (c0 + tx)]);
    }
    __syncthreads();
    for (int r = 0; r < 4; ++r) {
        int cl = ty + 8 * r;
        size_t idx = (size_t)(c0 + cl) * S_TOT + (s0 + tx);
        float val = ldin(x, idx, isf32) + tile[tx][cl];
        if (isf32) ((float*)out)[idx] = val;
        else       ((unsigned short*)out)[idx] = f2bf(val);
    }
}

extern "C" void kernel_launch(void* const* d_in, const int* in_sizes, int n_in,
                              void* d_out, int out_size, void* d_ws, size_t ws_size,
                              hipStream_t stream) {
    const void* x  = d_in[0];
    const void* Wq = d_in[1];
    const void* bq = d_in[2];
    const void* Wk = d_in[3];
    const void* bk = d_in[4];
    const void* Wv = d_in[5];
    const void* bv = d_in[6];
    const void* Wo = d_in[7];
    const void* bo = d_in[8];
    const void* gq = d_in[9];
    const void* gk = d_in[10];

    // ws ~40.5 MB: xn 11.9 | qb 11.9 | kb 11.9 | Ws 4.72 | vecs/stats/flag
    // Vt lives in d_out (dead before resid_t writes). ob:=xn, proj:=qb.
    char* ws = (char*)d_ws;
    size_t off = 0;
    auto alloc = [&](size_t bytes) -> char* {
        char* p = ws + off;
        off += (bytes + 255) & ~(size_t)255;
        return p;
    };
    const size_t SC = (size_t)S_TOT * C_DIM;
    unsigned short* xn   = (unsigned short*)alloc(SC * 2);
    unsigned short* qb   = (unsigned short*)alloc(SC * 2);
    unsigned short* kb   = (unsigned short*)alloc(SC * 2);
    unsigned short* Wsb  = (unsigned short*)alloc((size_t)C_DIM * C_DIM * 2);
    unsigned short* vecs = (unsigned short*)alloc((size_t)6 * C_DIM * 2);
    float* meanb         = (float*)alloc((size_t)S_TOT * 4);
    float* rstdb         = (float*)alloc((size_t)S_TOT * 4);
    int*   flag          = (int*)alloc(256);
    unsigned short* Vt   = (unsigned short*)d_out;   // [C][S] scratch in d_out
    unsigned short* ob   = xn;   // alias (xn dead after V-GEMM)
    unsigned short* proj = qb;   // alias (qb dead after attn)

    unsigned short* bq_b = vecs;
    unsigned short* bk_b = vecs + C_DIM;
    unsigned short* bv_b = vecs + 2 * C_DIM;
    unsigned short* bo_b = vecs + 3 * C_DIM;
    unsigned short* gq_b = vecs + 4 * C_DIM;
    unsigned short* gk_b = vecs + 5 * C_DIM;

    const float QSC = 0.12751747f;   // 1/sqrt(128) * log2(e)

    dim3 t328(32, 8);
    dim3 tgrid(S_TOT / 32, C_DIM / 32);               // (121, 48)
    dim3 ggrid((S_TOT + 127) / 128, C_DIM / 128);     // (31, 12)
    int wmg = (C_DIM * C_DIM) / 2048;                 // 1152

    detect<<<1, 256, 0, stream>>>((const unsigned short*)x, flag);
    wconv_vec<<<6, 256, 0, stream>>>(bq, bk, bv, bo, gq, gk, flag, vecs);
    ln_stats<<<NKT, 256, 0, stream>>>(x, flag, meanb, rstdb);
    ln_norm_t<<<tgrid, t328, 0, stream>>>(x, flag, meanb, rstdb, xn);

    wconv_mat<<<wmg, 256, 0, stream>>>(Wq, flag, Wsb);
    gemm128<<<ggrid, 256, 0, stream>>>(xn, Wsb, bq_b, qb, 0);
    rms_rope<<<S_TOT, 256, 0, stream>>>(qb, gq_b, QSC);

    wconv_mat<<<wmg, 256, 0, stream>>>(Wk, flag, Wsb);
    gemm128<<<ggrid, 256, 0, stream>>>(xn, Wsb, bk_b, kb, 0);
    rms_rope<<<S_TOT, 256, 0, stream>>>(kb, gk_b, 1.0f);

    wconv_mat<<<wmg, 256, 0, stream>>>(Wv, flag, Wsb);
    gemm128<<<ggrid, 256, 0, stream>>>(xn, Wsb, bv_b, Vt, 1);

    attn_mfma<<<NHEAD * NKT, 256, 0, stream>>>(qb, kb, Vt, ob);

    wconv_mat<<<wmg, 256, 0, stream>>>(Wo, flag, Wsb);
    gemm128<<<ggrid, 256, 0, stream>>>(ob, Wsb, bo_b, proj, 0);
    resid_t<<<tgrid, t328, 0, stream>>>(proj, x, flag, d_out);
}

// Round 6
// 666.562 us; speedup vs baseline: 17.4996x; 1.2208x over previous
//
#include <hip/hip_runtime.h>

#define S_TOT 3872
#define C_DIM 1536
#define NHEAD 12
#define DHEAD 128
#define TT 8
#define HH 22
#define WW 22
#define NKT 61          // ceil(3872/64)

typedef __bf16 bf16x8 __attribute__((ext_vector_type(8)));
typedef float  f32x4  __attribute__((ext_vector_type(4)));
typedef unsigned short u16x8 __attribute__((ext_vector_type(8)));

__device__ __forceinline__ float bf2f(unsigned short u) {
    unsigned int v = ((unsigned int)u) << 16;
    float f; __builtin_memcpy(&f, &v, 4); return f;
}
__device__ __forceinline__ unsigned short f2bf(float f) {
    unsigned int u; __builtin_memcpy(&u, &f, 4);
    u += 0x7fffu + ((u >> 16) & 1u);
    return (unsigned short)(u >> 16);
}
// truncation-pack two f32 -> bf16x2 dword (internal P only; 1-ulp bias ok)
__device__ __forceinline__ unsigned int pk2_trunc(float a, float b) {
    unsigned int ua, ub;
    __builtin_memcpy(&ua, &a, 4); __builtin_memcpy(&ub, &b, 4);
    return (ua >> 16) | (ub & 0xffff0000u);
}
__device__ __forceinline__ float ldin(const void* p, size_t i, int isf32) {
    if (isf32) return ((const float*)p)[i];
    return bf2f(((const unsigned short*)p)[i]);
}
__device__ __forceinline__ float fexp2(float x) {
#if __has_builtin(__builtin_amdgcn_exp2f)
    return __builtin_amdgcn_exp2f(x);
#else
    return exp2f(x);
#endif
}
__device__ __forceinline__ void async16(const void* g, void* l) {
    __builtin_amdgcn_global_load_lds(
        (const __attribute__((address_space(1))) unsigned int*)g,
        (__attribute__((address_space(3))) unsigned int*)l, 16, 0, 0);
}

// ------- dtype detector + bias/gain conversion (1 block) --------------
__global__ void detect_vecs(const unsigned short* __restrict__ x,
                            const void* p0, const void* p1, const void* p2,
                            const void* p3, const void* p4, const void* p5,
                            int* __restrict__ flag, unsigned short* __restrict__ vecs) {
    __shared__ int cnt;
    if (threadIdx.x == 0) cnt = 0;
    __syncthreads();
    int c = 0;
    for (int i = 0; i < 8; ++i) {
        unsigned short u = x[threadIdx.x * 8 + i];
        int e = (u >> 7) & 0xFF;
        if (e >= 112 && e <= 143) c++;
    }
    atomicAdd(&cnt, c);
    __syncthreads();
    int isf32 = (cnt >= 1900) ? 0 : 1;
    if (threadIdx.x == 0) *flag = isf32;
    const void* ps[6] = {p0, p1, p2, p3, p4, p5};
    for (int v = 0; v < 6; ++v)
        for (int j = threadIdx.x; j < C_DIM; j += 256)
            vecs[v * C_DIM + j] = f2bf(ldin(ps[v], j, isf32));
}

// -------- two weight matrices -> bf16, grid (1152, 2) -----------------
__global__ __launch_bounds__(256) void wconv2(const void* __restrict__ sA,
                                              const void* __restrict__ sB,
                                              const int* __restrict__ flag,
                                              unsigned short* __restrict__ dA,
                                              unsigned short* __restrict__ dB) {
    const void* src = blockIdx.y ? sB : sA;
    unsigned short* dst = blockIdx.y ? dB : dA;
    size_t i = ((size_t)blockIdx.x * 256 + threadIdx.x) * 8;
    if (*flag) {
        const float* s = (const float*)src + i;
        float4 a = *(const float4*)s, b = *(const float4*)(s + 4);
        u16x8 o;
        o[0]=f2bf(a.x); o[1]=f2bf(a.y); o[2]=f2bf(a.z); o[3]=f2bf(a.w);
        o[4]=f2bf(b.x); o[5]=f2bf(b.y); o[6]=f2bf(b.z); o[7]=f2bf(b.w);
        *(u16x8*)(dst + i) = o;
    } else {
        *(u16x8*)(dst + i) = *(const u16x8*)((const unsigned short*)src + i);
    }
}

// ---------------- LayerNorm stats: grid 61, block (64 s x 4 cg) -------
__global__ __launch_bounds__(256) void ln_stats(const void* __restrict__ x,
                                                const int* __restrict__ flag,
                                                float* __restrict__ meanb,
                                                float* __restrict__ rstdb) {
    int isf32 = *flag;
    int sl = threadIdx.x & 63, cg = threadIdx.x >> 6;
    int s = blockIdx.x * 64 + sl;
    float sum = 0.f, sumsq = 0.f;
    if (s < S_TOT) {
        for (int c = cg; c < C_DIM; c += 4) {
            float v = ldin(x, (size_t)c * S_TOT + s, isf32);
            sum += v; sumsq += v * v;
        }
    }
    __shared__ float r0[4][64], r1[4][64];
    r0[cg][sl] = sum; r1[cg][sl] = sumsq;
    __syncthreads();
    if (cg == 0 && s < S_TOT) {
        float st = r0[0][sl] + r0[1][sl] + r0[2][sl] + r0[3][sl];
        float sq = r1[0][sl] + r1[1][sl] + r1[2][sl] + r1[3][sl];
        float m = st * (1.0f / C_DIM);
        float var = sq * (1.0f / C_DIM) - m * m;
        meanb[s] = m;
        rstdb[s] = rsqrtf(var + 1e-6f);
    }
}

// ------------- Normalize + transpose (C,S) -> (S,C) bf16 --------------
__global__ __launch_bounds__(256) void ln_norm_t(const void* __restrict__ x,
                                                 const int* __restrict__ flag,
                                                 const float* __restrict__ meanb,
                                                 const float* __restrict__ rstdb,
                                                 unsigned short* __restrict__ xn) {
    int isf32 = *flag;
    __shared__ float tile[32][33];
    int s0 = blockIdx.x * 32, c0 = blockIdx.y * 32;
    int tx = threadIdx.x, ty = threadIdx.y;   // (32,8)
    for (int r = 0; r < 4; ++r) {
        int cl = ty + 8 * r;
        tile[cl][tx] = ldin(x, (size_t)(c0 + cl) * S_TOT + (s0 + tx), isf32);
    }
    __syncthreads();
    for (int r = 0; r < 4; ++r) {
        int sl = ty + 8 * r;
        int s = s0 + sl, c = c0 + tx;
        xn[(size_t)s * C_DIM + c] = f2bf((tile[tx][sl] - meanb[s]) * rstdb[s]);
    }
}

// ------- MFMA GEMM 64x128, BK=32, DMA staging; 732 blocks -------------
__global__ __launch_bounds__(256) void gemm64(const unsigned short* __restrict__ A,
                                              const unsigned short* __restrict__ W,
                                              const unsigned short* __restrict__ bias,
                                              unsigned short* __restrict__ D,
                                              int transV) {
    __shared__ __align__(16) unsigned short As[2048];   // 64 rows x 32
    __shared__ __align__(16) unsigned short Bs[4096];   // 128 rows x 32
    int m0 = blockIdx.x * 64, n0 = blockIdx.y * 128;
    int tid = threadIdx.x;
    int wave = tid >> 6, lane = tid & 63;
    int lm = lane & 15, lq = lane >> 4;
    int srow = lane >> 2, scol = (lane & 3) * 8;

    f32x4 acc[4][2];
    #pragma unroll
    for (int a = 0; a < 4; ++a)
        #pragma unroll
        for (int b = 0; b < 2; ++b) acc[a][b] = (f32x4){0.f, 0.f, 0.f, 0.f};

    for (int k0 = 0; k0 < C_DIM; k0 += 32) {
        __syncthreads();
        #pragma unroll
        for (int t = 0; t < 3; ++t) {
            int g = wave * 3 + t;   // 0..11
            if (g < 4) {
                int am = m0 + g * 16 + srow; if (am > S_TOT - 1) am = S_TOT - 1;
                async16(A + (size_t)am * C_DIM + k0 + scol, (char*)As + g * 1024);
            } else {
                int bn = n0 + (g - 4) * 16 + srow;
                async16(W + (size_t)bn * C_DIM + k0 + scol, (char*)Bs + (g - 4) * 1024);
            }
        }
        __syncthreads();
        bf16x8 af[4], bf[2];
        #pragma unroll
        for (int mb = 0; mb < 4; ++mb)
            af[mb] = *(const bf16x8*)((const char*)As + (mb * 16 + lm) * 64 + lq * 16);
        #pragma unroll
        for (int nb = 0; nb < 2; ++nb)
            bf[nb] = *(const bf16x8*)((const char*)Bs + (wave * 32 + nb * 16 + lm) * 64 + lq * 16);
        #pragma unroll
        for (int mb = 0; mb < 4; ++mb)
            #pragma unroll
            for (int nb = 0; nb < 2; ++nb)
                acc[mb][nb] = __builtin_amdgcn_mfma_f32_16x16x32_bf16(af[mb], bf[nb], acc[mb][nb], 0, 0, 0);
    }

    if (!transV) {
        #pragma unroll
        for (int mb = 0; mb < 4; ++mb)
            #pragma unroll
            for (int nb = 0; nb < 2; ++nb) {
                int gn = n0 + wave * 32 + nb * 16 + lm;
                float bv = bf2f(bias[gn]);
                #pragma unroll
                for (int r = 0; r < 4; ++r) {
                    int gm = m0 + mb * 16 + lq * 4 + r;
                    if (gm < S_TOT) D[(size_t)gm * C_DIM + gn] = f2bf(acc[mb][nb][r] + bv);
                }
            }
    } else {
        #pragma unroll
        for (int mb = 0; mb < 4; ++mb) {
            int gm0 = m0 + mb * 16 + lq * 4;
            if (gm0 >= S_TOT) continue;
            #pragma unroll
            for (int nb = 0; nb < 2; ++nb) {
                int gn = n0 + wave * 32 + nb * 16 + lm;
                float bv = bf2f(bias[gn]);
                ushort4 pk;
                pk.x = f2bf(acc[mb][nb][0] + bv);
                pk.y = f2bf(acc[mb][nb][1] + bv);
                pk.z = f2bf(acc[mb][nb][2] + bv);
                pk.w = f2bf(acc[mb][nb][3] + bv);
                *(ushort4*)(D + (size_t)gn * S_TOT + gm0) = pk;
            }
        }
    }
}

// ---------- RMSNorm + RoPE for Q and K in one launch, in-place --------
__global__ __launch_bounds__(256) void rope2(unsigned short* __restrict__ qbuf,
                                             unsigned short* __restrict__ kbuf,
                                             const unsigned short* __restrict__ gq,
                                             const unsigned short* __restrict__ gk,
                                             float qsc) {
    int s = blockIdx.x;
    unsigned short* row = (blockIdx.y ? kbuf : qbuf) + (size_t)s * C_DIM;
    const unsigned short* g = blockIdx.y ? gk : gq;
    float premul = blockIdx.y ? 1.0f : qsc;
    int tid = threadIdx.x;
    float ss = 0.f;
    for (int i = 0; i < 6; ++i) {
        float v = bf2f(row[tid + 256 * i]);
        ss += v * v;
    }
    for (int off = 32; off; off >>= 1) ss += __shfl_down(ss, off, 64);
    __shared__ float wsum[4];
    __shared__ float scale_sh;
    if ((tid & 63) == 0) wsum[tid >> 6] = ss;
    __syncthreads();
    if (tid == 0) {
        float tot = wsum[0] + wsum[1] + wsum[2] + wsum[3];
        scale_sh = rsqrtf(tot * (1.0f / C_DIM) + 1e-6f) * premul;
    }
    __syncthreads();
    float scale = scale_sh;

    int t  = s / (HH * WW);
    int rm = s % (HH * WW);
    int hh = rm / WW, ww = rm % WW;

    float e[3][2];
    int cols[3];
    for (int i = 0; i < 3; ++i) {
        int p = tid + 256 * i;
        int j = p & 63;
        int col0 = (p >> 6) * DHEAD + 2 * j;
        cols[i] = col0;
        float e0 = bf2f(row[col0])     * scale * bf2f(g[col0]);
        float e1 = bf2f(row[col0 + 1]) * scale * bf2f(g[col0 + 1]);
        float pos, fr;
        if (j < 22)       { pos = (float)t;  fr = (float)j        * (1.0f / 22.0f); }
        else if (j < 43)  { pos = (float)hh; fr = (float)(j - 22) * (1.0f / 21.0f); }
        else              { pos = (float)ww; fr = (float)(j - 43) * (1.0f / 21.0f); }
        float ang = pos * expf(fr * -9.210340371976184f);
        float c = cosf(ang), sn = sinf(ang);
        e[i][0] = e0 * c - e1 * sn;
        e[i][1] = e0 * sn + e1 * c;
    }
    for (int i = 0; i < 3; ++i) {
        row[cols[i]]     = f2bf(e[i][0]);
        row[cols[i] + 1] = f2bf(e[i][1]);
    }
}

// ---------------- MFMA flash attention v3 (S^T orientation) -----------
// S^T = K*Q^T (swap mfma args); each lane owns one q-column -> scalar
// softmax state. PV as O^T = V^T * P^T with plain stride-88 LDS (<=2-way).
// LDS 49.5 KB -> 3 blocks/CU.
__global__ __launch_bounds__(256) void attn_mfma(const unsigned short* __restrict__ q,
                                                 const unsigned short* __restrict__ kp,
                                                 const unsigned short* __restrict__ vt,
                                                 unsigned short* __restrict__ o) {
    __shared__ __align__(16) unsigned char Ks[16896];      // 16 groups * 1056B
    __shared__ __align__(16) unsigned short Vs[128 * 88];  // [d][keys], pad 24
    __shared__ __align__(16) unsigned short Ps[4][16 * 88];// [wave][q][keys]

    int h  = blockIdx.x / NKT;
    int qt = blockIdx.x % NKT;
    int q0 = qt * 64;
    int tid = threadIdx.x;
    int wave = tid >> 6, lane = tid & 63;
    int lm = lane & 15, lq = lane >> 4;

    // Q as B-operand fragments (lane = q-col, regs = d); pre-scaled by qsc
    bf16x8 qf[4];
    {
        int qr = q0 + wave * 16 + lm; if (qr >= S_TOT) qr = S_TOT - 1;
        const unsigned short* qptr = q + (size_t)qr * C_DIM + h * DHEAD + lq * 8;
        #pragma unroll
        for (int kc = 0; kc < 4; ++kc) qf[kc] = *(const bf16x8*)(qptr + kc * 32);
    }

    // K DMA constants
    int kgrow = lane >> 4;
    size_t kcol = (size_t)(h * DHEAD + (lane & 15) * 8);
    // V staging constants
    int vd  = tid >> 1;              // 0..127
    int vk0 = (tid & 1) * 32;
    const unsigned short* vrow = vt + (size_t)(h * DHEAD + vd) * S_TOT;
    // K frag read offsets (bytes)
    int ksoff[4], kqoff[4];
    #pragma unroll
    for (int nt = 0; nt < 4; ++nt) ksoff[nt] = (nt * 4 + (lm >> 2)) * 1056 + (lm & 3) * 256;
    #pragma unroll
    for (int kc = 0; kc < 4; ++kc) kqoff[kc] = (kc * 4 + lq) * 16;

    f32x4 oacc[8];
    #pragma unroll
    for (int i = 0; i < 8; ++i) oacc[i] = (f32x4){0.f, 0.f, 0.f, 0.f};
    float m_run = -__builtin_inff(), l_run = 0.f;   // scalar: one q per lane

    for (int kt = 0; kt < NKT; ++kt) {
        int k0 = kt * 64;
        __syncthreads();               // prev tile's Ks/Vs reads complete
        // K tile DMA (16 groups of 4 rows x 128 d)
        #pragma unroll
        for (int t = 0; t < 4; ++t) {
            int g = wave * 4 + t;
            int grow = k0 + g * 4 + kgrow; if (grow > S_TOT - 1) grow = S_TOT - 1;
            async16(kp + (size_t)grow * C_DIM + kcol, Ks + g * 1056);
        }
        // V tile: 4 x uint4 per thread, plain [d][key] stride 88
        #pragma unroll
        for (int c = 0; c < 4; ++c) {
            int gk = k0 + vk0 + c * 8; if (gk > S_TOT - 8) gk = S_TOT - 8;
            uint4 val = *(const uint4*)(vrow + gk);
            *(uint4*)(&Vs[vd * 88 + vk0 + c * 8]) = val;
        }
        __syncthreads();               // DMA + V loads drained, LDS visible

        // S^T[key][q]: sacc[nt] covers keys nt*16.., cols = q
        f32x4 sacc[4];
        #pragma unroll
        for (int nt = 0; nt < 4; ++nt) sacc[nt] = (f32x4){0.f, 0.f, 0.f, 0.f};
        #pragma unroll
        for (int kc = 0; kc < 4; ++kc)
            #pragma unroll
            for (int nt = 0; nt < 4; ++nt) {
                bf16x8 kf = *(const bf16x8*)(Ks + ksoff[nt] + kqoff[kc]);
                sacc[nt] = __builtin_amdgcn_mfma_f32_16x16x32_bf16(kf, qf[kc], sacc[nt], 0, 0, 0);
            }
        // mask tail keys
        if (kt == NKT - 1) {
            #pragma unroll
            for (int nt = 0; nt < 4; ++nt)
                #pragma unroll
                for (int r = 0; r < 4; ++r)
                    if (k0 + nt * 16 + lq * 4 + r >= S_TOT) sacc[nt][r] = -__builtin_inff();
        }
        // online softmax, base-2, scalar state (q = lm)
        float rmax = sacc[0][0];
        #pragma unroll
        for (int nt = 0; nt < 4; ++nt)
            #pragma unroll
            for (int r = 0; r < 4; ++r) rmax = fmaxf(rmax, sacc[nt][r]);
        rmax = fmaxf(rmax, __shfl_xor(rmax, 16, 64));
        rmax = fmaxf(rmax, __shfl_xor(rmax, 32, 64));
        float mn = fmaxf(m_run, rmax);
        float alpha = fexp2(m_run - mn);
        float rs = 0.f;
        #pragma unroll
        for (int nt = 0; nt < 4; ++nt)
            #pragma unroll
            for (int r = 0; r < 4; ++r) {
                float p = fexp2(sacc[nt][r] - mn);
                sacc[nt][r] = p;
                rs += p;
            }
        rs += __shfl_xor(rs, 16, 64);
        rs += __shfl_xor(rs, 32, 64);
        l_run = l_run * alpha + rs;
        m_run = mn;
        // P^T -> per-wave LDS: row q=lm, keys nt*16+lq*4.. (2 dwords = b64)
        #pragma unroll
        for (int nt = 0; nt < 4; ++nt) {
            uint2 pk;
            pk.x = pk2_trunc(sacc[nt][0], sacc[nt][1]);
            pk.y = pk2_trunc(sacc[nt][2], sacc[nt][3]);
            *(uint2*)(&Ps[wave][lm * 88 + nt * 16 + lq * 4]) = pk;
        }
        // rescale O^T
        #pragma unroll
        for (int i = 0; i < 8; ++i)
            #pragma unroll
            for (int r = 0; r < 4; ++r) oacc[i][r] *= alpha;
        // PV: O^T[d][q] += V^T[d][key] * P^T[key][q]  (Ps wave-private)
        #pragma unroll
        for (int kc = 0; kc < 2; ++kc) {
            bf16x8 pf = *(const bf16x8*)(&Ps[wave][lm * 88 + kc * 32 + lq * 8]);
            #pragma unroll
            for (int mt = 0; mt < 8; ++mt) {
                bf16x8 vf = *(const bf16x8*)(&Vs[(mt * 16 + lm) * 88 + kc * 32 + lq * 8]);
                oacc[mt] = __builtin_amdgcn_mfma_f32_16x16x32_bf16(vf, pf, oacc[mt], 0, 0, 0);
            }
        }
    }
    // epilogue: lane owns q-column; d runs over mt/lq/r -> ushort4 stores
    int qrow = q0 + wave * 16 + lm;
    if (qrow < S_TOT) {
        float inv = 1.0f / l_run;
        #pragma unroll
        for (int mt = 0; mt < 8; ++mt) {
            ushort4 pk;
            pk.x = f2bf(oacc[mt][0] * inv);
            pk.y = f2bf(oacc[mt][1] * inv);
            pk.z = f2bf(oacc[mt][2] * inv);
            pk.w = f2bf(oacc[mt][3] * inv);
            *(ushort4*)(o + (size_t)qrow * C_DIM + h * DHEAD + mt * 16 + lq * 4) = pk;
        }
    }
}

// ------ Residual + transpose (S,C) bf16 -> (C,S) out (dual dtype) -----
__global__ __launch_bounds__(256) void resid_t(const unsigned short* __restrict__ proj,
                                               const void* __restrict__ x,
                                               const int* __restrict__ flag,
                                               void* __restrict__ out) {
    int isf32 = *flag;
    __shared__ float tile[32][33];
    int s0 = blockIdx.x * 32, c0 = blockIdx.y * 32;
    int tx = threadIdx.x, ty = threadIdx.y;   // (32,8)
    for (int r = 0; r < 4; ++r) {
        int sl = ty + 8 * r;
        tile[sl][tx] = bf2f(proj[(size_t)(s0 + sl) * C_DIM + (c0 + tx)]);
    }
    __syncthreads();
    for (int r = 0; r < 4; ++r) {
        int cl = ty + 8 * r;
        size_t idx = (size_t)(c0 + cl) * S_TOT + (s0 + tx);
        float val = ldin(x, idx, isf32) + tile[tx][cl];
        if (isf32) ((float*)out)[idx] = val;
        else       ((unsigned short*)out)[idx] = f2bf(val);
    }
}

extern "C" void kernel_launch(void* const* d_in, const int* in_sizes, int n_in,
                              void* d_out, int out_size, void* d_ws, size_t ws_size,
                              hipStream_t stream) {
    const void* x  = d_in[0];
    const void* Wq = d_in[1];
    const void* bq = d_in[2];
    const void* Wk = d_in[3];
    const void* bk = d_in[4];
    const void* Wv = d_in[5];
    const void* bv = d_in[6];
    const void* Wo = d_in[7];
    const void* bo = d_in[8];
    const void* gq = d_in[9];
    const void* gk = d_in[10];

    // ws ~45.2 MB: xn 11.9 | qb 11.9 | kb 11.9 | Wslot0+1 9.4 | small
    char* ws = (char*)d_ws;
    size_t off = 0;
    auto alloc = [&](size_t bytes) -> char* {
        char* p = ws + off;
        off += (bytes + 255) & ~(size_t)255;
        return p;
    };
    const size_t SC = (size_t)S_TOT * C_DIM;
    unsigned short* xn   = (unsigned short*)alloc(SC * 2);
    unsigned short* qb   = (unsigned short*)alloc(SC * 2);
    unsigned short* kb   = (unsigned short*)alloc(SC * 2);
    unsigned short* Ws0  = (unsigned short*)alloc((size_t)C_DIM * C_DIM * 2);
    unsigned short* Ws1  = (unsigned short*)alloc((size_t)C_DIM * C_DIM * 2);
    unsigned short* vecs = (unsigned short*)alloc((size_t)6 * C_DIM * 2);
    float* meanb         = (float*)alloc((size_t)S_TOT * 4);
    float* rstdb         = (float*)alloc((size_t)S_TOT * 4);
    int*   flag          = (int*)alloc(256);
    unsigned short* Vt   = (unsigned short*)d_out;   // [C][S] scratch in d_out
    unsigned short* ob   = xn;   // alias (xn dead after V-GEMM)
    unsigned short* proj = qb;   // alias (qb dead after attn)

    unsigned short* bq_b = vecs;
    unsigned short* bk_b = vecs + C_DIM;
    unsigned short* bv_b = vecs + 2 * C_DIM;
    unsigned short* bo_b = vecs + 3 * C_DIM;
    unsigned short* gq_b = vecs + 4 * C_DIM;
    unsigned short* gk_b = vecs + 5 * C_DIM;

    const float QSC = 0.12751745f;   // 1/sqrt(128) * log2(e)

    dim3 t328(32, 8);
    dim3 tgrid(S_TOT / 32, C_DIM / 32);             // (121, 48)
    dim3 ggrid((S_TOT + 63) / 64, C_DIM / 128);     // (61, 12)
    dim3 wgrid((C_DIM * C_DIM) / 2048, 2);          // (1152, 2)
    dim3 rgrid(S_TOT, 2);

    detect_vecs<<<1, 256, 0, stream>>>((const unsigned short*)x, bq, bk, bv, bo, gq, gk, flag, vecs);
    wconv2<<<wgrid, 256, 0, stream>>>(Wq, Wk, flag, Ws0, Ws1);
    ln_stats<<<NKT, 256, 0, stream>>>(x, flag, meanb, rstdb);
    ln_norm_t<<<tgrid, t328, 0, stream>>>(x, flag, meanb, rstdb, xn);

    gemm64<<<ggrid, 256, 0, stream>>>(xn, Ws0, bq_b, qb, 0);
    gemm64<<<ggrid, 256, 0, stream>>>(xn, Ws1, bk_b, kb, 0);
    rope2<<<rgrid, 256, 0, stream>>>(qb, kb, gq_b, gk_b, QSC);

    wconv2<<<wgrid, 256, 0, stream>>>(Wv, Wo, flag, Ws0, Ws1);  // slots free again
    gemm64<<<ggrid, 256, 0, stream>>>(xn, Ws0, bv_b, Vt, 1);

    attn_mfma<<<NHEAD * NKT, 256, 0, stream>>>(qb, kb, Vt, ob);

    gemm64<<<ggrid, 256, 0, stream>>>(ob, Ws1, bo_b, proj, 0);
    resid_t<<<tgrid, t328, 0, stream>>>(proj, x, flag, d_out);
}